// Round 11
// baseline (698.068 us; speedup 1.0000x reference)
//
#include <hip/hip_runtime.h>
#include <stdint.h>

// ============================================================================
// INSTRUMENTATION ROUND: kernels are byte-identical in algorithm to R10, but
// gemm_g repeats its body 12x and gather_out 4x (idempotent rewrites of the
// same values) so their dispatches exceed the ~205us harness memsets and
// appear in rocprof top-5 with per-kernel FETCH/WRITE/dur. dur_us this round
// is NOT a perf number. Next round reverts REP to 1 and acts on the counters.
// ============================================================================

#define REP_GEMM 12
#define REP_GATHER 4

typedef short bf16x8 __attribute__((ext_vector_type(8)));
typedef float f32x4  __attribute__((ext_vector_type(4)));
typedef float f32x2  __attribute__((ext_vector_type(2)));

__device__ __forceinline__ unsigned short f2bf(float f) {
    unsigned int u = __float_as_uint(f);
    u += 0x7FFFu + ((u >> 16) & 1u);
    return (unsigned short)(u >> 16);
}
__device__ __forceinline__ float bf2f(unsigned short h) {
    return __uint_as_float(((unsigned int)h) << 16);
}

// ---- kernel A: fold W1f = w1@wf, W2f = w2@wf (store transposed bf16), cb = b@wf ----
__global__ void fuse_weights(const float* __restrict__ w1, const float* __restrict__ b1,
                             const float* __restrict__ w2, const float* __restrict__ b2,
                             const float* __restrict__ wf,
                             unsigned short* __restrict__ wcT,  // [2][128 cols][128 k]
                             float* __restrict__ cb)            // [2][128]
{
    int mat = blockIdx.x / 129;
    int kk  = blockIdx.x % 129;
    int c   = threadIdx.x;
    const float* w = (mat == 0) ? w1 : w2;
    const float* b = (mat == 0) ? b1 : b2;
    float acc = 0.f;
    if (kk < 128) {
        #pragma unroll 8
        for (int j = 0; j < 128; ++j) acc += w[kk * 128 + j] * wf[j * 128 + c];
        wcT[mat * 16384 + c * 128 + kk] = f2bf(acc);
    } else {
        #pragma unroll 8
        for (int j = 0; j < 128; ++j) acc += b[j] * wf[j * 128 + c];
        cb[mat * 128 + c] = acc;
    }
}

// ---- kernel B (R3 form + REP): g[mat] = x @ Wc[mat] + cb[mat] -> bf16 ----
#define WAVE_ROWS 64
__global__ __launch_bounds__(256) void gemm_g(
    const float* __restrict__ x, const unsigned short* __restrict__ wcT,
    const float* __restrict__ cb, unsigned short* __restrict__ g, int nrows)
{
    int lane = threadIdx.x & 63;
    int wid  = threadIdx.x >> 6;
    int r0   = (blockIdx.x * 4 + wid) * WAVE_ROWS;
    if (r0 >= nrows) return;
    int lrow = lane & 15;
    int kg   = lane >> 4;

    #pragma unroll 1
    for (int rep = 0; rep < REP_GEMM; ++rep) {
        asm volatile("" ::: "memory");   // keep iterations distinct (no merge/DCE)

        bf16x8 xf[4][4];   // [rowtile][kstep]
        #pragma unroll
        for (int t = 0; t < 4; ++t) {
            int row = r0 + t * 16 + lrow;
            bool v  = row < nrows;
            #pragma unroll
            for (int ks = 0; ks < 4; ++ks) {
                int k0 = ks * 32 + kg * 8;
                float4 p0 = v ? *(const float4*)(x + (size_t)row * 128 + k0)     : float4{0,0,0,0};
                float4 p1 = v ? *(const float4*)(x + (size_t)row * 128 + k0 + 4) : float4{0,0,0,0};
                bf16x8 f;
                f[0] = (short)f2bf(p0.x); f[1] = (short)f2bf(p0.y);
                f[2] = (short)f2bf(p0.z); f[3] = (short)f2bf(p0.w);
                f[4] = (short)f2bf(p1.x); f[5] = (short)f2bf(p1.y);
                f[6] = (short)f2bf(p1.z); f[7] = (short)f2bf(p1.w);
                xf[t][ks] = f;
            }
        }

        #pragma unroll
        for (int mat = 0; mat < 2; ++mat) {
            unsigned short* gm = g + (size_t)mat * nrows * 128;
            const unsigned short* wT = wcT + mat * 16384;
            #pragma unroll 2
            for (int c = 0; c < 8; ++c) {
                bf16x8 wfr[4];
                const unsigned short* wb = wT + (size_t)(c * 16 + lrow) * 128 + kg * 8;
                #pragma unroll
                for (int ks = 0; ks < 4; ++ks)
                    wfr[ks] = *(const bf16x8*)(wb + ks * 32);
                f32x4 acc[4];
                #pragma unroll
                for (int t = 0; t < 4; ++t) acc[t] = f32x4{0,0,0,0};
                #pragma unroll
                for (int ks = 0; ks < 4; ++ks) {
                    #pragma unroll
                    for (int t = 0; t < 4; ++t)
                        acc[t] = __builtin_amdgcn_mfma_f32_16x16x32_bf16(wfr[ks], xf[t][ks], acc[t], 0,0,0);
                }
                float4 bias = *(const float4*)(cb + mat * 128 + c * 16 + kg * 4);
                #pragma unroll
                for (int t = 0; t < 4; ++t) {
                    int xrow = r0 + t * 16 + lrow;
                    if (xrow < nrows) {
                        ushort4 o;
                        o.x = f2bf(acc[t][0] + bias.x); o.y = f2bf(acc[t][1] + bias.y);
                        o.z = f2bf(acc[t][2] + bias.z); o.w = f2bf(acc[t][3] + bias.w);
                        *(ushort4*)(gm + (size_t)xrow * 128 + c * 16 + kg * 4) = o;
                    }
                }
            }
        }
    }
}

// ---- kernel C (R3 form + REP): one wave per node; wave-uniform deg ----
__global__ __launch_bounds__(256) void gather_out(
    const int* __restrict__ ci, const unsigned short* __restrict__ g,
    const float* __restrict__ bfv, float* __restrict__ out,
    float* __restrict__ maskout, int nnodes)
{
    int n    = (int)((blockIdx.x * blockDim.x + threadIdx.x) >> 6);
    int lane = threadIdx.x & 63;
    if (n >= nnodes) return;

    #pragma unroll 1
    for (int rep = 0; rep < REP_GATHER; ++rep) {
        asm volatile("" ::: "memory");   // keep iterations distinct (no merge/DCE)

        int civ = ci[n * 8 + (lane & 7)];
        unsigned long long bal = __ballot(civ == -1);
        int cnt = __popcll(bal & 0xFFull);
        int deg = (cnt == 8) ? 0 : (7 - cnt);     // wave-uniform

        int d = lane * 2;
        float2 bfd = *(const float2*)(bfv + d);
        const unsigned short* g1 = g;
        const unsigned short* g2 = g + (size_t)nnodes * 128;

        unsigned ua[7], ub[7];
        #pragma unroll
        for (int k = 0; k < 7; ++k) {
            int i = __shfl(civ, k);
            ua[k] = (k < deg) ? *(const unsigned*)(g1 + (size_t)i * 128 + d) : 0u;
        }
        bool two = (deg >= 2);
        #pragma unroll
        for (int k = 1; k < 8; ++k) {
            int i = __shfl(civ, k);
            ub[k - 1] = (two && k <= deg) ? *(const unsigned*)(g2 + (size_t)i * 128 + d) : 0u;
        }

        size_t outbase = (size_t)n * 7 * 128;
        #pragma unroll
        for (int j = 0; j < 7; ++j) {
            float s0 = bfd.x + bf2f((unsigned short)(ua[j] & 0xFFFFu))
                             + bf2f((unsigned short)(ub[j] & 0xFFFFu));
            float s1 = bfd.y + bf2f((unsigned short)(ua[j] >> 16))
                             + bf2f((unsigned short)(ub[j] >> 16));
            f32x2 o; o[0] = s0; o[1] = s1;
            __builtin_nontemporal_store(o, (f32x2*)(out + outbase + (size_t)j * 128 + d));
        }
        if (lane < 7)
            __builtin_nontemporal_store((lane < deg) ? 1.0f : 0.0f, maskout + n * 7 + lane);
    }
}

extern "C" void kernel_launch(void* const* d_in, const int* in_sizes, int n_in,
                              void* d_out, int out_size, void* d_ws, size_t ws_size,
                              hipStream_t stream) {
    const float* x   = (const float*)d_in[0];
    const float* w1  = (const float*)d_in[1];
    const float* b1  = (const float*)d_in[2];
    const float* w2  = (const float*)d_in[3];
    const float* b2  = (const float*)d_in[4];
    const float* wf  = (const float*)d_in[5];
    const float* bfv = (const float*)d_in[6];
    const int*   ci  = (const int*)d_in[7];

    int nrows = in_sizes[0] / 128;

    size_t gbytes = (size_t)2 * nrows * 128 * 2;
    unsigned short* g   = (unsigned short*)d_ws;
    unsigned short* wcT = (unsigned short*)((char*)d_ws + ((gbytes + 255) & ~(size_t)255));
    float*          cb  = (float*)((char*)wcT + 2 * 128 * 128 * 2);

    fuse_weights<<<2 * 129, 128, 0, stream>>>(w1, b1, w2, b2, wf, wcT, cb);

    int nblk = (nrows + 4 * WAVE_ROWS - 1) / (4 * WAVE_ROWS);
    gemm_g<<<nblk, 256, 0, stream>>>(x, wcT, cb, g, nrows);

    int rows = nrows * 7;
    int cblk = (nrows * 64 + 255) / 256;
    float* out = (float*)d_out;
    gather_out<<<cblk, 256, 0, stream>>>(ci, g, bfv, out, out + (size_t)rows * 128, nrows);
}

// Round 12
// 132.158 us; speedup vs baseline: 5.2821x; 5.2821x over previous
//
#include <hip/hip_runtime.h>
#include <stdint.h>

typedef short bf16x8 __attribute__((ext_vector_type(8)));
typedef float f32x4  __attribute__((ext_vector_type(4)));
typedef float f32x2  __attribute__((ext_vector_type(2)));

__device__ __forceinline__ unsigned short f2bf(float f) {
    unsigned int u = __float_as_uint(f);
    u += 0x7FFFu + ((u >> 16) & 1u);
    return (unsigned short)(u >> 16);
}
__device__ __forceinline__ float bf2f(unsigned short h) {
    return __uint_as_float(((unsigned int)h) << 16);
}

// ---- kernel A: fold W1f = w1@wf, W2f = w2@wf (store transposed bf16), cb = b@wf ----
__global__ void fuse_weights(const float* __restrict__ w1, const float* __restrict__ b1,
                             const float* __restrict__ w2, const float* __restrict__ b2,
                             const float* __restrict__ wf,
                             unsigned short* __restrict__ wcT,  // [2][128 cols][128 k]
                             float* __restrict__ cb)            // [2][128]
{
    int mat = blockIdx.x / 129;
    int kk  = blockIdx.x % 129;
    int c   = threadIdx.x;
    const float* w = (mat == 0) ? w1 : w2;
    const float* b = (mat == 0) ? b1 : b2;
    float acc = 0.f;
    if (kk < 128) {
        #pragma unroll 8
        for (int j = 0; j < 128; ++j) acc += w[kk * 128 + j] * wf[j * 128 + c];
        wcT[mat * 16384 + c * 128 + kk] = f2bf(acc);
    } else {
        #pragma unroll 8
        for (int j = 0; j < 128; ++j) acc += b[j] * wf[j * 128 + c];
        cb[mat * 128 + c] = acc;
    }
}

// ---- kernel B: g[mat] = x @ Wc[mat] + cb[mat] -> bf16 [2][nrows][128] ----
// MAT-SPLIT: blockIdx.x = (tile << 1) | mat. Each wave loads its 64 x-rows
// (32 dwordx4 in flight) but computes only ONE mat -> 2x waves, 2x bytes in
// flight (latency fix per R11 counters: 16% occupancy, 3 TB/s, MFMA 7%).
// Paired block (other mat, same tile) re-reads the same x rows via L3.
#define WAVE_ROWS 64
__global__ __launch_bounds__(256) void gemm_g(
    const float* __restrict__ x, const unsigned short* __restrict__ wcT,
    const float* __restrict__ cb, unsigned short* __restrict__ g, int nrows)
{
    int lane = threadIdx.x & 63;
    int wid  = threadIdx.x >> 6;
    int bid  = blockIdx.x;
    int mat  = bid & 1;
    int tile = bid >> 1;
    int r0   = (tile * 4 + wid) * WAVE_ROWS;
    if (r0 >= nrows) return;
    int lrow = lane & 15;
    int kg   = lane >> 4;

    bf16x8 xf[4][4];   // [rowtile][kstep]
    #pragma unroll
    for (int t = 0; t < 4; ++t) {
        int row = r0 + t * 16 + lrow;
        bool v  = row < nrows;
        #pragma unroll
        for (int ks = 0; ks < 4; ++ks) {
            int k0 = ks * 32 + kg * 8;
            float4 p0 = v ? *(const float4*)(x + (size_t)row * 128 + k0)     : float4{0,0,0,0};
            float4 p1 = v ? *(const float4*)(x + (size_t)row * 128 + k0 + 4) : float4{0,0,0,0};
            bf16x8 f;
            f[0] = (short)f2bf(p0.x); f[1] = (short)f2bf(p0.y);
            f[2] = (short)f2bf(p0.z); f[3] = (short)f2bf(p0.w);
            f[4] = (short)f2bf(p1.x); f[5] = (short)f2bf(p1.y);
            f[6] = (short)f2bf(p1.z); f[7] = (short)f2bf(p1.w);
            xf[t][ks] = f;
        }
    }

    unsigned short* gm = g + (size_t)mat * nrows * 128;
    const unsigned short* wT = wcT + mat * 16384;
    #pragma unroll 2
    for (int c = 0; c < 8; ++c) {
        bf16x8 wfr[4];
        const unsigned short* wb = wT + (size_t)(c * 16 + lrow) * 128 + kg * 8;
        #pragma unroll
        for (int ks = 0; ks < 4; ++ks)
            wfr[ks] = *(const bf16x8*)(wb + ks * 32);
        f32x4 acc[4];
        #pragma unroll
        for (int t = 0; t < 4; ++t) acc[t] = f32x4{0,0,0,0};
        #pragma unroll
        for (int ks = 0; ks < 4; ++ks) {
            #pragma unroll
            for (int t = 0; t < 4; ++t)
                acc[t] = __builtin_amdgcn_mfma_f32_16x16x32_bf16(wfr[ks], xf[t][ks], acc[t], 0,0,0);
        }
        float4 bias = *(const float4*)(cb + mat * 128 + c * 16 + kg * 4);
        #pragma unroll
        for (int t = 0; t < 4; ++t) {
            int xrow = r0 + t * 16 + lrow;
            if (xrow < nrows) {
                ushort4 o;
                o.x = f2bf(acc[t][0] + bias.x); o.y = f2bf(acc[t][1] + bias.y);
                o.z = f2bf(acc[t][2] + bias.z); o.w = f2bf(acc[t][3] + bias.w);
                *(ushort4*)(gm + (size_t)xrow * 128 + c * 16 + kg * 4) = o;
            }
        }
    }
}

// ---- kernel C (R3 form): one wave per node; wave-uniform deg -> loads for
//      k >= deg fully skipped by scalar branches. Split load/consume. ----
__global__ __launch_bounds__(256) void gather_out(
    const int* __restrict__ ci, const unsigned short* __restrict__ g,
    const float* __restrict__ bfv, float* __restrict__ out,
    float* __restrict__ maskout, int nnodes)
{
    int n    = (int)((blockIdx.x * blockDim.x + threadIdx.x) >> 6);
    int lane = threadIdx.x & 63;
    if (n >= nnodes) return;

    int civ = ci[n * 8 + (lane & 7)];
    unsigned long long bal = __ballot(civ == -1);
    int cnt = __popcll(bal & 0xFFull);
    int deg = (cnt == 8) ? 0 : (7 - cnt);     // wave-uniform

    int d = lane * 2;
    float2 bfd = *(const float2*)(bfv + d);
    const unsigned short* g1 = g;
    const unsigned short* g2 = g + (size_t)nnodes * 128;

    // load phase: all needed rows in flight before any consumption.
    unsigned ua[7], ub[7];
    #pragma unroll
    for (int k = 0; k < 7; ++k) {
        int i = __shfl(civ, k);
        ua[k] = (k < deg) ? *(const unsigned*)(g1 + (size_t)i * 128 + d) : 0u;
    }
    bool two = (deg >= 2);
    #pragma unroll
    for (int k = 1; k < 8; ++k) {
        int i = __shfl(civ, k);
        ub[k - 1] = (two && k <= deg) ? *(const unsigned*)(g2 + (size_t)i * 128 + d) : 0u;
    }

    // consume + store phase (branch-free adds; zero bits are exact no-ops)
    size_t outbase = (size_t)n * 7 * 128;
    #pragma unroll
    for (int j = 0; j < 7; ++j) {
        float s0 = bfd.x + bf2f((unsigned short)(ua[j] & 0xFFFFu))
                         + bf2f((unsigned short)(ub[j] & 0xFFFFu));
        float s1 = bfd.y + bf2f((unsigned short)(ua[j] >> 16))
                         + bf2f((unsigned short)(ub[j] >> 16));
        f32x2 o; o[0] = s0; o[1] = s1;
        __builtin_nontemporal_store(o, (f32x2*)(out + outbase + (size_t)j * 128 + d));
    }
    if (lane < 7)
        __builtin_nontemporal_store((lane < deg) ? 1.0f : 0.0f, maskout + n * 7 + lane);
}

extern "C" void kernel_launch(void* const* d_in, const int* in_sizes, int n_in,
                              void* d_out, int out_size, void* d_ws, size_t ws_size,
                              hipStream_t stream) {
    const float* x   = (const float*)d_in[0];
    const float* w1  = (const float*)d_in[1];
    const float* b1  = (const float*)d_in[2];
    const float* w2  = (const float*)d_in[3];
    const float* b2  = (const float*)d_in[4];
    const float* wf  = (const float*)d_in[5];
    const float* bfv = (const float*)d_in[6];
    const int*   ci  = (const int*)d_in[7];

    int nrows = in_sizes[0] / 128;

    size_t gbytes = (size_t)2 * nrows * 128 * 2;
    unsigned short* g   = (unsigned short*)d_ws;
    unsigned short* wcT = (unsigned short*)((char*)d_ws + ((gbytes + 255) & ~(size_t)255));
    float*          cb  = (float*)((char*)wcT + 2 * 128 * 128 * 2);

    fuse_weights<<<2 * 129, 128, 0, stream>>>(w1, b1, w2, b2, wf, wcT, cb);

    int ntiles = (nrows + 4 * WAVE_ROWS - 1) / (4 * WAVE_ROWS);
    gemm_g<<<ntiles * 2, 256, 0, stream>>>(x, wcT, cb, g, nrows);

    int rows = nrows * 7;
    int cblk = (nrows * 64 + 255) / 256;
    float* out = (float*)d_out;
    gather_out<<<cblk, 256, 0, stream>>>(ci, g, bfv, out, out + (size_t)rows * 128, nrows);
}

// Round 13
// 114.016 us; speedup vs baseline: 6.1225x; 1.1591x over previous
//
#include <hip/hip_runtime.h>
#include <stdint.h>

typedef short bf16x8 __attribute__((ext_vector_type(8)));
typedef float f32x4  __attribute__((ext_vector_type(4)));
typedef float f32x2  __attribute__((ext_vector_type(2)));

__device__ __forceinline__ unsigned short f2bf(float f) {
    unsigned int u = __float_as_uint(f);
    u += 0x7FFFu + ((u >> 16) & 1u);
    return (unsigned short)(u >> 16);
}
__device__ __forceinline__ float bf2f(unsigned short h) {
    return __uint_as_float(((unsigned int)h) << 16);
}

// ---- kernel A: fold W1f = w1@wf, W2f = w2@wf (store transposed bf16), cb = b@wf ----
__global__ void fuse_weights(const float* __restrict__ w1, const float* __restrict__ b1,
                             const float* __restrict__ w2, const float* __restrict__ b2,
                             const float* __restrict__ wf,
                             unsigned short* __restrict__ wcT,  // [2][128 cols][128 k]
                             float* __restrict__ cb)            // [2][128]
{
    int mat = blockIdx.x / 129;
    int kk  = blockIdx.x % 129;
    int c   = threadIdx.x;
    const float* w = (mat == 0) ? w1 : w2;
    const float* b = (mat == 0) ? b1 : b2;
    float acc = 0.f;
    if (kk < 128) {
        #pragma unroll 8
        for (int j = 0; j < 128; ++j) acc += w[kk * 128 + j] * wf[j * 128 + c];
        wcT[mat * 16384 + c * 128 + kk] = f2bf(acc);
    } else {
        #pragma unroll 8
        for (int j = 0; j < 128; ++j) acc += b[j] * wf[j * 128 + c];
        cb[mat * 128 + c] = acc;
    }
}

// ---- kernel B: g[mat] = x @ Wc[mat] + cb[mat] -> bf16 [2][nrows][128] ----
// R13: wcT (64 KB, both mats) staged in LDS once per block with XOR swizzle
// (byte ^= (col&7)<<4) so the 16-lane col-stride-256B fragment reads are
// conflict-free ds_read_b128. Kills the per-c-iteration L2 round-trip that
// R11 counters identified as the stall (occ 15.8%, MFMA 7%, 3 TB/s).
#define WAVE_ROWS 64
__global__ __launch_bounds__(256) void gemm_g(
    const float* __restrict__ x, const unsigned short* __restrict__ wcT,
    const float* __restrict__ cb, unsigned short* __restrict__ g, int nrows)
{
    __shared__ uint4 ldsw[4096];   // 64 KB: [2 mats][128 cols][128 k] bf16, swizzled

    int tid  = threadIdx.x;
    int lane = tid & 63;
    int wid  = tid >> 6;
    int r0   = (blockIdx.x * 4 + wid) * WAVE_ROWS;
    int lrow = lane & 15;
    int kg   = lane >> 4;
    int swz  = (lrow & 7) << 4;    // wave-constant per lane

    // ---- cooperative LDS fill with XOR swizzle on bits 4-6 of byte addr ----
    const uint4* w4 = (const uint4*)wcT;
    #pragma unroll
    for (int i = 0; i < 16; ++i) {
        int idx = tid + i * 256;               // uint4 index, 0..4095
        uint4 v = w4[idx];
        int b   = idx << 4;                    // byte addr
        int sb  = b ^ (((b >> 8) & 7) << 4);   // (col&7)<<4 swizzle
        ldsw[sb >> 4] = v;
    }

    if (r0 < nrows) {
        // x fragment loads (overlap with LDS fill latency)
        bf16x8 xf[4][4];   // [rowtile][kstep]
        #pragma unroll
        for (int t = 0; t < 4; ++t) {
            int row = r0 + t * 16 + lrow;
            bool v  = row < nrows;
            #pragma unroll
            for (int ks = 0; ks < 4; ++ks) {
                int k0 = ks * 32 + kg * 8;
                float4 p0 = v ? *(const float4*)(x + (size_t)row * 128 + k0)     : float4{0,0,0,0};
                float4 p1 = v ? *(const float4*)(x + (size_t)row * 128 + k0 + 4) : float4{0,0,0,0};
                bf16x8 f;
                f[0] = (short)f2bf(p0.x); f[1] = (short)f2bf(p0.y);
                f[2] = (short)f2bf(p0.z); f[3] = (short)f2bf(p0.w);
                f[4] = (short)f2bf(p1.x); f[5] = (short)f2bf(p1.y);
                f[6] = (short)f2bf(p1.z); f[7] = (short)f2bf(p1.w);
                xf[t][ks] = f;
            }
        }

        __syncthreads();

        const char* lbase = (const char*)ldsw;
        #pragma unroll
        for (int mat = 0; mat < 2; ++mat) {
            unsigned short* gm = g + (size_t)mat * nrows * 128;
            int mb = mat * 32768;
            #pragma unroll 2
            for (int c = 0; c < 8; ++c) {
                int colb = mb + (c * 16 + lrow) * 256 + kg * 16;
                bf16x8 wfr[4];
                #pragma unroll
                for (int ks = 0; ks < 4; ++ks)
                    wfr[ks] = *(const bf16x8*)(lbase + ((colb + ks * 64) ^ swz));
                f32x4 acc[4];
                #pragma unroll
                for (int t = 0; t < 4; ++t) acc[t] = f32x4{0,0,0,0};
                #pragma unroll
                for (int ks = 0; ks < 4; ++ks) {
                    #pragma unroll
                    for (int t = 0; t < 4; ++t)
                        acc[t] = __builtin_amdgcn_mfma_f32_16x16x32_bf16(wfr[ks], xf[t][ks], acc[t], 0,0,0);
                }
                float4 bias = *(const float4*)(cb + mat * 128 + c * 16 + kg * 4);
                #pragma unroll
                for (int t = 0; t < 4; ++t) {
                    int xrow = r0 + t * 16 + lrow;
                    if (xrow < nrows) {
                        ushort4 o;
                        o.x = f2bf(acc[t][0] + bias.x); o.y = f2bf(acc[t][1] + bias.y);
                        o.z = f2bf(acc[t][2] + bias.z); o.w = f2bf(acc[t][3] + bias.w);
                        *(ushort4*)(gm + (size_t)xrow * 128 + c * 16 + kg * 4) = o;
                    }
                }
            }
        }
    }
}

// ---- kernel C (R3 form): one wave per node; wave-uniform deg -> loads for
//      k >= deg fully skipped by scalar branches. Split load/consume. ----
__global__ __launch_bounds__(256) void gather_out(
    const int* __restrict__ ci, const unsigned short* __restrict__ g,
    const float* __restrict__ bfv, float* __restrict__ out,
    float* __restrict__ maskout, int nnodes)
{
    int n    = (int)((blockIdx.x * blockDim.x + threadIdx.x) >> 6);
    int lane = threadIdx.x & 63;
    if (n >= nnodes) return;

    int civ = ci[n * 8 + (lane & 7)];
    unsigned long long bal = __ballot(civ == -1);
    int cnt = __popcll(bal & 0xFFull);
    int deg = (cnt == 8) ? 0 : (7 - cnt);     // wave-uniform

    int d = lane * 2;
    float2 bfd = *(const float2*)(bfv + d);
    const unsigned short* g1 = g;
    const unsigned short* g2 = g + (size_t)nnodes * 128;

    // load phase: all needed rows in flight before any consumption.
    unsigned ua[7], ub[7];
    #pragma unroll
    for (int k = 0; k < 7; ++k) {
        int i = __shfl(civ, k);
        ua[k] = (k < deg) ? *(const unsigned*)(g1 + (size_t)i * 128 + d) : 0u;
    }
    bool two = (deg >= 2);
    #pragma unroll
    for (int k = 1; k < 8; ++k) {
        int i = __shfl(civ, k);
        ub[k - 1] = (two && k <= deg) ? *(const unsigned*)(g2 + (size_t)i * 128 + d) : 0u;
    }

    // consume + store phase (branch-free adds; zero bits are exact no-ops)
    size_t outbase = (size_t)n * 7 * 128;
    #pragma unroll
    for (int j = 0; j < 7; ++j) {
        float s0 = bfd.x + bf2f((unsigned short)(ua[j] & 0xFFFFu))
                         + bf2f((unsigned short)(ub[j] & 0xFFFFu));
        float s1 = bfd.y + bf2f((unsigned short)(ua[j] >> 16))
                         + bf2f((unsigned short)(ub[j] >> 16));
        f32x2 o; o[0] = s0; o[1] = s1;
        __builtin_nontemporal_store(o, (f32x2*)(out + outbase + (size_t)j * 128 + d));
    }
    if (lane < 7)
        __builtin_nontemporal_store((lane < deg) ? 1.0f : 0.0f, maskout + n * 7 + lane);
}

extern "C" void kernel_launch(void* const* d_in, const int* in_sizes, int n_in,
                              void* d_out, int out_size, void* d_ws, size_t ws_size,
                              hipStream_t stream) {
    const float* x   = (const float*)d_in[0];
    const float* w1  = (const float*)d_in[1];
    const float* b1  = (const float*)d_in[2];
    const float* w2  = (const float*)d_in[3];
    const float* b2  = (const float*)d_in[4];
    const float* wf  = (const float*)d_in[5];
    const float* bfv = (const float*)d_in[6];
    const int*   ci  = (const int*)d_in[7];

    int nrows = in_sizes[0] / 128;

    size_t gbytes = (size_t)2 * nrows * 128 * 2;
    unsigned short* g   = (unsigned short*)d_ws;
    unsigned short* wcT = (unsigned short*)((char*)d_ws + ((gbytes + 255) & ~(size_t)255));
    float*          cb  = (float*)((char*)wcT + 2 * 128 * 128 * 2);

    fuse_weights<<<2 * 129, 128, 0, stream>>>(w1, b1, w2, b2, wf, wcT, cb);

    int ntiles = (nrows + 4 * WAVE_ROWS - 1) / (4 * WAVE_ROWS);
    gemm_g<<<ntiles, 256, 0, stream>>>(x, wcT, cb, g, nrows);

    int rows = nrows * 7;
    int cblk = (nrows * 64 + 255) / 256;
    float* out = (float*)d_out;
    gather_out<<<cblk, 256, 0, stream>>>(ci, g, bfv, out, out + (size_t)rows * 128, nrows);
}

// Round 14
// 112.148 us; speedup vs baseline: 6.2246x; 1.0167x over previous
//
#include <hip/hip_runtime.h>
#include <stdint.h>

typedef short bf16x8 __attribute__((ext_vector_type(8)));
typedef float f32x4  __attribute__((ext_vector_type(4)));

__device__ __forceinline__ unsigned short f2bf(float f) {
    unsigned int u = __float_as_uint(f);
    u += 0x7FFFu + ((u >> 16) & 1u);
    return (unsigned short)(u >> 16);
}
__device__ __forceinline__ float bf2f(unsigned short h) {
    return __uint_as_float(((unsigned int)h) << 16);
}

// ---- kernel A: fold W1f = w1@wf, W2f = w2@wf (store transposed bf16), cb = b@wf ----
__global__ void fuse_weights(const float* __restrict__ w1, const float* __restrict__ b1,
                             const float* __restrict__ w2, const float* __restrict__ b2,
                             const float* __restrict__ wf,
                             unsigned short* __restrict__ wcT,  // [2][128 cols][128 k]
                             float* __restrict__ cb)            // [2][128]
{
    int mat = blockIdx.x / 129;
    int kk  = blockIdx.x % 129;
    int c   = threadIdx.x;
    const float* w = (mat == 0) ? w1 : w2;
    const float* b = (mat == 0) ? b1 : b2;
    float acc = 0.f;
    if (kk < 128) {
        #pragma unroll 8
        for (int j = 0; j < 128; ++j) acc += w[kk * 128 + j] * wf[j * 128 + c];
        wcT[mat * 16384 + c * 128 + kk] = f2bf(acc);
    } else {
        #pragma unroll 8
        for (int j = 0; j < 128; ++j) acc += b[j] * wf[j * 128 + c];
        cb[mat * 128 + c] = acc;
    }
}

// ---- kernel B: g[mat] = x @ Wc[mat] + cb[mat] -> bf16 [2][nrows][128] ----
// R14: 512-thread blocks (8 waves x 32 rows). Same 64KB swizzled-LDS wcT as
// R13, but 2 blocks/CU resident -> ~4 waves/SIMD (was 1.5) to overlap the
// cold x loads and LDS fill. Fill cost amortized over 2x threads.
#define WAVE_ROWS 32
__global__ __launch_bounds__(512) void gemm_g(
    const float* __restrict__ x, const unsigned short* __restrict__ wcT,
    const float* __restrict__ cb, unsigned short* __restrict__ g, int nrows)
{
    __shared__ uint4 ldsw[4096];   // 64 KB: [2 mats][128 cols][128 k] bf16, swizzled

    int tid  = threadIdx.x;
    int lane = tid & 63;
    int wid  = tid >> 6;
    int r0   = (blockIdx.x * 8 + wid) * WAVE_ROWS;
    int lrow = lane & 15;
    int kg   = lane >> 4;
    int swz  = (lrow & 7) << 4;    // wave-constant per lane

    // ---- cooperative LDS fill with XOR swizzle on byte bits 4-6 ----
    const uint4* w4 = (const uint4*)wcT;
    #pragma unroll
    for (int i = 0; i < 8; ++i) {
        int idx = tid + i * 512;               // uint4 index, 0..4095
        uint4 v = w4[idx];
        int b   = idx << 4;                    // byte addr
        int sb  = b ^ (((b >> 8) & 7) << 4);   // (col&7)<<4 swizzle
        ldsw[sb >> 4] = v;
    }

    // x fragment loads (overlap with LDS fill latency); per-row guards
    bf16x8 xf[2][4];   // [rowtile][kstep]
    #pragma unroll
    for (int t = 0; t < 2; ++t) {
        int row = r0 + t * 16 + lrow;
        bool v  = row < nrows;
        #pragma unroll
        for (int ks = 0; ks < 4; ++ks) {
            int k0 = ks * 32 + kg * 8;
            float4 p0 = v ? *(const float4*)(x + (size_t)row * 128 + k0)     : float4{0,0,0,0};
            float4 p1 = v ? *(const float4*)(x + (size_t)row * 128 + k0 + 4) : float4{0,0,0,0};
            bf16x8 f;
            f[0] = (short)f2bf(p0.x); f[1] = (short)f2bf(p0.y);
            f[2] = (short)f2bf(p0.z); f[3] = (short)f2bf(p0.w);
            f[4] = (short)f2bf(p1.x); f[5] = (short)f2bf(p1.y);
            f[6] = (short)f2bf(p1.z); f[7] = (short)f2bf(p1.w);
            xf[t][ks] = f;
        }
    }

    __syncthreads();
    if (r0 >= nrows) return;

    const char* lbase = (const char*)ldsw;
    #pragma unroll
    for (int mat = 0; mat < 2; ++mat) {
        unsigned short* gm = g + (size_t)mat * nrows * 128;
        int mb = mat * 32768;
        #pragma unroll 2
        for (int c = 0; c < 8; ++c) {
            int colb = mb + (c * 16 + lrow) * 256 + kg * 16;
            bf16x8 wfr[4];
            #pragma unroll
            for (int ks = 0; ks < 4; ++ks)
                wfr[ks] = *(const bf16x8*)(lbase + ((colb + ks * 64) ^ swz));
            f32x4 acc[2];
            #pragma unroll
            for (int t = 0; t < 2; ++t) acc[t] = f32x4{0,0,0,0};
            #pragma unroll
            for (int ks = 0; ks < 4; ++ks) {
                #pragma unroll
                for (int t = 0; t < 2; ++t)
                    acc[t] = __builtin_amdgcn_mfma_f32_16x16x32_bf16(wfr[ks], xf[t][ks], acc[t], 0,0,0);
            }
            float4 bias = *(const float4*)(cb + mat * 128 + c * 16 + kg * 4);
            #pragma unroll
            for (int t = 0; t < 2; ++t) {
                int xrow = r0 + t * 16 + lrow;
                if (xrow < nrows) {
                    ushort4 o;
                    o.x = f2bf(acc[t][0] + bias.x); o.y = f2bf(acc[t][1] + bias.y);
                    o.z = f2bf(acc[t][2] + bias.z); o.w = f2bf(acc[t][3] + bias.w);
                    *(ushort4*)(gm + (size_t)xrow * 128 + c * 16 + kg * 4) = o;
                }
            }
        }
    }
}

// ---- kernel C: one wave per node, CHUNKED. Output row-block (7x128 f32 =
// 3.5KB contiguous) stored as 3 full 1KB f32x4 chunks + 1 half chunk.
// Lane covers 4 dims: chunk c -> row r = 2c+(lane>>5), dims (lane&31)*4.
// Loads: <=8 uint2 (same bytes as before, half the instructions), same
// proven wave-uniform scalar skip + exec-masked predication. ----
__global__ __launch_bounds__(256) void gather_out(
    const int* __restrict__ ci, const unsigned short* __restrict__ g,
    const float* __restrict__ bfv, float* __restrict__ out,
    float* __restrict__ maskout, int nnodes)
{
    int n    = (int)((blockIdx.x * blockDim.x + threadIdx.x) >> 6);
    int lane = threadIdx.x & 63;
    if (n >= nnodes) return;

    int civ = ci[n * 8 + (lane & 7)];
    unsigned long long bal = __ballot(civ == -1);
    int cnt = __popcll(bal & 0xFFull);
    int deg = (cnt == 8) ? 0 : (7 - cnt);     // wave-uniform

    int half = lane >> 5;
    int hl   = lane & 31;
    int d4   = hl * 4;                        // 4 dims per lane
    float4 bfd = *(const float4*)(bfv + d4);
    const unsigned short* g1 = g;
    const unsigned short* g2 = g + (size_t)nnodes * 128;
    bool two = (deg >= 2);

    // ---- load phase: all needed rows in flight before any consumption ----
    uint2 va[4], vb[4];
    #pragma unroll
    for (int c = 0; c < 4; ++c) {
        va[c] = uint2{0u, 0u};
        vb[c] = uint2{0u, 0u};
        if (2 * c < deg) {                    // wave-uniform skip
            int r  = 2 * c + half;            // row 0..7 (row 7 always masked)
            int i0 = __shfl(civ, r);
            int i1 = __shfl(civ, r + 1);
            bool m = (r < deg);
            va[c] = m          ? *(const uint2*)(g1 + (size_t)i0 * 128 + d4) : uint2{0u, 0u};
            vb[c] = (m && two) ? *(const uint2*)(g2 + (size_t)i1 * 128 + d4) : uint2{0u, 0u};
        }
    }

    // ---- consume + store (branch-free adds; zero bits are exact no-ops) ----
    size_t base = (size_t)n * 896;            // 7*128
    #pragma unroll
    for (int c = 0; c < 4; ++c) {
        f32x4 o;
        o[0] = bfd.x + bf2f((unsigned short)(va[c].x & 0xFFFFu)) + bf2f((unsigned short)(vb[c].x & 0xFFFFu));
        o[1] = bfd.y + bf2f((unsigned short)(va[c].x >> 16))     + bf2f((unsigned short)(vb[c].x >> 16));
        o[2] = bfd.z + bf2f((unsigned short)(va[c].y & 0xFFFFu)) + bf2f((unsigned short)(vb[c].y & 0xFFFFu));
        o[3] = bfd.w + bf2f((unsigned short)(va[c].y >> 16))     + bf2f((unsigned short)(vb[c].y >> 16));
        if (c < 3)
            __builtin_nontemporal_store(o, (f32x4*)(out + base + c * 256 + lane * 4));
        else if (half == 0)
            __builtin_nontemporal_store(o, (f32x4*)(out + base + 768 + hl * 4));
    }
    if (lane < 7)
        __builtin_nontemporal_store((lane < deg) ? 1.0f : 0.0f, maskout + n * 7 + lane);
}

extern "C" void kernel_launch(void* const* d_in, const int* in_sizes, int n_in,
                              void* d_out, int out_size, void* d_ws, size_t ws_size,
                              hipStream_t stream) {
    const float* x   = (const float*)d_in[0];
    const float* w1  = (const float*)d_in[1];
    const float* b1  = (const float*)d_in[2];
    const float* w2  = (const float*)d_in[3];
    const float* b2  = (const float*)d_in[4];
    const float* wf  = (const float*)d_in[5];
    const float* bfv = (const float*)d_in[6];
    const int*   ci  = (const int*)d_in[7];

    int nrows = in_sizes[0] / 128;

    size_t gbytes = (size_t)2 * nrows * 128 * 2;
    unsigned short* g   = (unsigned short*)d_ws;
    unsigned short* wcT = (unsigned short*)((char*)d_ws + ((gbytes + 255) & ~(size_t)255));
    float*          cb  = (float*)((char*)wcT + 2 * 128 * 128 * 2);

    fuse_weights<<<2 * 129, 128, 0, stream>>>(w1, b1, w2, b2, wf, wcT, cb);

    int nblk = (nrows + 8 * WAVE_ROWS - 1) / (8 * WAVE_ROWS);
    gemm_g<<<nblk, 512, 0, stream>>>(x, wcT, cb, g, nrows);

    int rows = nrows * 7;
    int cblk = (nrows * 64 + 255) / 256;
    float* out = (float*)d_out;
    gather_out<<<cblk, 256, 0, stream>>>(ci, g, bfv, out, out + (size_t)rows * 128, nrows);
}